// Round 2
// baseline (1033.239 us; speedup 1.0000x reference)
//
#include <hip/hip_runtime.h>

// Problem constants
#define NTOK 49          // window tokens (7x7)
#define NW   64          // number of distinct masks
#define SCALEQ 0.17677669529663687f   // 32^-0.5

typedef __bf16 bf16;
typedef __bf16 bf16x4 __attribute__((ext_vector_type(4)));
typedef __bf16 bf16x8 __attribute__((ext_vector_type(8)));
typedef float  f32x4  __attribute__((ext_vector_type(4)));

// ---- LDS layout (units: bf16 elements) ----
// qk  : [4][3920]  per LOCAL head: q [49][40] | k [49][40].
//                  P [49][72] (3528 elems) aliases this after frag-load barrier.
// vts : [4][32][56] v transposed [dd][m], m pad 49..55 zeroed   off 15680 (7168)
// xs  : [49][264]   staged x bf16                               off 22848 (12936)
// ost : [49][264]   attention output (phase 3/4) aliases qk region
// total = 35784 elems = 71568 B -> 2 blocks/CU (143136 <= 163840)
#define QK_OFF  0
#define QK_H    3920
#define K_SUB   1960
#define P_LD    72
#define VTS_OFF 15680
#define XS_OFF  22848
#define SMEM_ELEMS 35784
#define SMEM_BYTES (SMEM_ELEMS*2)
static_assert(SMEM_BYTES == 71568, "lds budget");

// Prep: convert weights to bf16, expand relative-position bias to [8][49][49]
__global__ __launch_bounds__(256) void prep_kernel(
    const float* __restrict__ qkv_w, const float* __restrict__ proj_w,
    const float* __restrict__ bias_table, const int* __restrict__ rel_index,
    bf16* __restrict__ wq, bf16* __restrict__ wp, float* __restrict__ bias_full)
{
  int i = blockIdx.x * 256 + threadIdx.x;
  if (i < 768*256) wq[i] = (bf16)qkv_w[i];
  if (i < 256*256) wp[i] = (bf16)proj_w[i];
  if (i < 8*49*49) {
    int h  = i / 2401;
    int nm = i - h*2401;
    bias_full[i] = bias_table[rel_index[nm]*8 + h];
  }
}

__global__ void __launch_bounds__(512, 4)
win_attn_kernel(const float* __restrict__ x,
                const float* __restrict__ mask,
                const float* __restrict__ qkv_b,
                const float* __restrict__ proj_b,
                const bf16*  __restrict__ wq,
                const bf16*  __restrict__ wp,
                const float* __restrict__ bias_full,
                float* __restrict__ out)
{
  extern __shared__ bf16 smem[];
  const int b    = blockIdx.x;
  const int tid  = threadIdx.x;
  const int wave = tid >> 6;      // 0..7
  const int lane = tid & 63;
  const int quad = lane >> 4;
  const int l16  = lane & 15;
  const int w    = b & (NW - 1);   // mask window index

  bf16* qk  = smem + QK_OFF;
  bf16* vts = smem + VTS_OFF;
  bf16* xs  = smem + XS_OFF;

  f32x4 zero4 = {0.f, 0.f, 0.f, 0.f};

  // ---------- phase 0: stage x -> bf16 LDS; zero vts pads (once, pads never rewritten) ----------
  {
    const float4* xv = (const float4*)(x + (size_t)b * (NTOK*256));  // 3136 vec4
    for (int i = tid; i < NTOK*64; i += 512) {
      float4 v = xv[i];
      int n = i >> 6, c = (i & 63) * 4;
      bf16x4 pk = {(bf16)v.x, (bf16)v.y, (bf16)v.z, (bf16)v.w};
      *(bf16x4*)(xs + n*264 + c) = pk;
    }
    for (int i = tid; i < 4*32*7; i += 512) {      // vts m in [49,56) := 0
      int hh = i / 224, r = i - hh*224;
      int dd = r / 7, mm = 49 + (r - dd*7);
      vts[(hh*32 + dd)*56 + mm] = (bf16)0.0f;
    }
  }
  __syncthreads();

  const int hl   = wave >> 1;     // local head 0..3
  const int half = wave & 1;

  // Named per-head-group accumulators: NEVER indexed by a runtime value.
  // (Round-1 lesson: O[hg] under a partially-unrolled barrier loop went to
  //  scratch -> 550 MB of HBM spill traffic. Lambda + literal hg fixes it.)
  f32x4 O0[2][2], O1[2][2];

  auto head_group = [&](const int hg, f32x4 (&O)[2][2]) {
    // ---------- phase 1: qkv GEMM for heads hg*4..hg*4+3 (24 col-tiles, 3/wave) ----------
    {
      f32x4 acc[3][4];
#pragma unroll
      for (int t = 0; t < 3; ++t)
#pragma unroll
        for (int tr = 0; tr < 4; ++tr) acc[t][tr] = zero4;

      const bf16* wrow[3];
      int jc_[3], s_[3], tl_[3];
#pragma unroll
      for (int t = 0; t < 3; ++t) {
        int tt = wave*3 + t;                 // 0..23
        s_[t]  = tt >> 3;                    // 0=q 1=k 2=v
        tl_[t] = tt & 7;                     // tile within segment
        jc_[t] = s_[t]*256 + hg*128 + tl_[t]*16 + l16;   // 0..767
        wrow[t] = wq + (size_t)jc_[t]*256 + quad*8;
      }
#pragma unroll
      for (int kk = 0; kk < 8; ++kk) {
        bf16x8 afr[4];
#pragma unroll
        for (int tr = 0; tr < 4; ++tr) {
          int m = tr*16 + l16; if (m > 48) m = 48;   // rows>=49 discarded
          afr[tr] = *(const bf16x8*)(xs + m*264 + quad*8 + kk*32);
        }
#pragma unroll
        for (int t = 0; t < 3; ++t) {
          bf16x8 bfr = *(const bf16x8*)(wrow[t] + kk*32);
#pragma unroll
          for (int tr = 0; tr < 4; ++tr)
            acc[t][tr] = __builtin_amdgcn_mfma_f32_16x16x32_bf16(afr[tr], bfr, acc[t][tr], 0,0,0);
        }
      }
#pragma unroll
      for (int t = 0; t < 3; ++t) {
        float bj = qkv_b[jc_[t]];
        int hh = tl_[t] >> 1;                // local head
        int dd = jc_[t] & 31;
#pragma unroll
        for (int tr = 0; tr < 4; ++tr)
#pragma unroll
          for (int rg = 0; rg < 4; ++rg) {
            int row = tr*16 + quad*4 + rg;   // C layout: row=quad*4+reg
            if (row < 49) {
              float v = acc[t][tr][rg] + bj;
              if (s_[t] == 0)      qk[hh*QK_H + row*40 + dd] = (bf16)(v * SCALEQ);
              else if (s_[t] == 1) qk[hh*QK_H + K_SUB + row*40 + dd] = (bf16)v;
              else                 vts[(hh*32 + dd)*56 + row] = (bf16)v;
            }
          }
      }
    }
    __syncthreads();

    // ---------- phase 2: attention; wave pair per local head ----------
    {
      const int h = hg*4 + hl;               // global head
      const bf16* qh = qk  + hl*QK_H;
      const bf16* kh = qh + K_SUB;
      const bf16* vh = vts + hl*(32*56);
      bf16* Pb = qk + hl*QK_H;               // P aliases q|k after frag loads

      bf16x8 qf[2], kf[4];
#pragma unroll
      for (int t = 0; t < 2; ++t) {
        int m = (half*2 + t)*16 + l16; if (m > 48) m = 48;
        qf[t] = *(const bf16x8*)(qh + m*40 + quad*8);
      }
#pragma unroll
      for (int t = 0; t < 4; ++t) {
        int m = t*16 + l16; if (m > 48) m = 48;
        kf[t] = *(const bf16x8*)(kh + m*40 + quad*8);
      }
      __syncthreads();        // all q/k frag reads done before P overlays them

      f32x4 S[2][4];
#pragma unroll
      for (int tr = 0; tr < 2; ++tr)
#pragma unroll
        for (int tc = 0; tc < 4; ++tc)
          S[tr][tc] = __builtin_amdgcn_mfma_f32_16x16x32_bf16(qf[tr], kf[tc], zero4, 0,0,0);

      const float* bh = bias_full + h*2401;
      const float* mw = mask + w*2401;
#pragma unroll
      for (int tr2 = 0; tr2 < 2; ++tr2) {
        int tr = half*2 + tr2;
#pragma unroll
        for (int rg = 0; rg < 4; ++rg) {
          int row = tr*16 + quad*4 + rg;
#pragma unroll
          for (int tc = 0; tc < 4; ++tc) {
            int col = tc*16 + l16;
            float v = S[tr2][tc][rg];
            if (col >= 49) v = -1e30f;                 // pad cols -> exact 0 after exp
            else if (row < 49) {
              int idx = row*49 + col;
              v += bh[idx] + mw[idx];
            }
            S[tr2][tc][rg] = v;
          }
          float mx = fmaxf(fmaxf(S[tr2][0][rg], S[tr2][1][rg]),
                           fmaxf(S[tr2][2][rg], S[tr2][3][rg]));
#pragma unroll
          for (int off = 1; off < 16; off <<= 1)
            mx = fmaxf(mx, __shfl_xor(mx, off));
          float sum = 0.f;
#pragma unroll
          for (int tc = 0; tc < 4; ++tc) {
            float p = __expf(S[tr2][tc][rg] - mx);
            S[tr2][tc][rg] = p;
            sum += p;
          }
#pragma unroll
          for (int off = 1; off < 16; off <<= 1)
            sum += __shfl_xor(sum, off);
          float inv = 1.f / sum;
          if (row < 49) {                              // rows>=49 never stored
#pragma unroll
            for (int tc = 0; tc < 4; ++tc)
              Pb[row*P_LD + tc*16 + l16] = (bf16)(S[tr2][tc][rg] * inv);
          }
        }
      }

      // O = P @ V   (wave reads only P rows it wrote; DS in-order per wave)
      O[0][0] = zero4; O[0][1] = zero4;
      O[1][0] = zero4; O[1][1] = zero4;
#pragma unroll
      for (int kst = 0; kst < 2; ++kst) {
        int mc  = kst*32 + quad*8;
        int mcv = (mc >= 56) ? 0 : mc;                 // P cols 56..63 are 0
        bf16x8 vf0 = *(const bf16x8*)(vh + l16*56 + mcv);
        bf16x8 vf1 = *(const bf16x8*)(vh + (16 + l16)*56 + mcv);
#pragma unroll
        for (int tr2 = 0; tr2 < 2; ++tr2) {
          int row = (half*2 + tr2)*16 + l16; if (row > 48) row = 48;
          bf16x8 pf = *(const bf16x8*)(Pb + row*P_LD + mc);
          O[tr2][0] = __builtin_amdgcn_mfma_f32_16x16x32_bf16(pf, vf0, O[tr2][0], 0,0,0);
          O[tr2][1] = __builtin_amdgcn_mfma_f32_16x16x32_bf16(pf, vf1, O[tr2][1], 0,0,0);
        }
      }
    }
    __syncthreads();    // all P/V reads done before next hg rewrites qk/vts (or ost aliases)
  };

  head_group(0, O0);
  head_group(1, O1);

  // ---------- phase 3: O -> ost [49][264] (token-major, channel = h*32+dd) ----------
  bf16* ost = smem;     // aliases qk region (12936 <= 15680)
  {
    int h0 = hl;        // hg=0 global head
    int h1 = 4 + hl;    // hg=1 global head
#pragma unroll
    for (int tr2 = 0; tr2 < 2; ++tr2)
#pragma unroll
      for (int rg = 0; rg < 4; ++rg) {
        int row = (half*2 + tr2)*16 + quad*4 + rg;
        if (row < 49) {
          ost[row*264 + h0*32 + l16]      = (bf16)O0[tr2][0][rg];
          ost[row*264 + h0*32 + 16 + l16] = (bf16)O0[tr2][1][rg];
          ost[row*264 + h1*32 + l16]      = (bf16)O1[tr2][0][rg];
          ost[row*264 + h1*32 + 16 + l16] = (bf16)O1[tr2][1][rg];
        }
      }
  }
  __syncthreads();

  // ---------- phase 4: out = ost @ Wproj^T + b; wave owns two 16-col tiles ----------
  {
    f32x4 acc[2][4];
#pragma unroll
    for (int t = 0; t < 2; ++t)
#pragma unroll
      for (int tr = 0; tr < 4; ++tr) acc[t][tr] = zero4;
    int oc[2];
    const bf16* wrow[2];
#pragma unroll
    for (int t = 0; t < 2; ++t) {
      oc[t] = (wave*2 + t)*16 + l16;                   // 0..255
      wrow[t] = wp + (size_t)oc[t]*256 + quad*8;
    }
#pragma unroll
    for (int kk = 0; kk < 8; ++kk) {
      bf16x8 afr[4];
#pragma unroll
      for (int tr = 0; tr < 4; ++tr) {
        int m = tr*16 + l16; if (m > 48) m = 48;
        afr[tr] = *(const bf16x8*)(ost + m*264 + quad*8 + kk*32);
      }
#pragma unroll
      for (int t = 0; t < 2; ++t) {
        bf16x8 bfr = *(const bf16x8*)(wrow[t] + kk*32);
#pragma unroll
        for (int tr = 0; tr < 4; ++tr)
          acc[t][tr] = __builtin_amdgcn_mfma_f32_16x16x32_bf16(afr[tr], bfr, acc[t][tr], 0,0,0);
      }
    }
    float* ob = out + (size_t)b * (NTOK*256);
#pragma unroll
    for (int t = 0; t < 2; ++t) {
      float bj = proj_b[oc[t]];
#pragma unroll
      for (int tr = 0; tr < 4; ++tr)
#pragma unroll
        for (int rg = 0; rg < 4; ++rg) {
          int row = tr*16 + quad*4 + rg;
          if (row < 49) ob[row*256 + oc[t]] = acc[t][tr][rg] + bj;
        }
    }
  }
}

extern "C" void kernel_launch(void* const* d_in, const int* in_sizes, int n_in,
                              void* d_out, int out_size, void* d_ws, size_t ws_size,
                              hipStream_t stream) {
  const float* x          = (const float*)d_in[0];
  const float* mask       = (const float*)d_in[1];
  const float* qkv_w      = (const float*)d_in[2];
  const float* qkv_b      = (const float*)d_in[3];
  const float* proj_w     = (const float*)d_in[4];
  const float* proj_b     = (const float*)d_in[5];
  const float* bias_table = (const float*)d_in[6];
  const int*   rel_index  = (const int*)d_in[7];
  float* out = (float*)d_out;

  // workspace: wq bf16 [768*256] | wp bf16 [256*256] | bias_full f32 [8*49*49]
  bf16*  wq        = (bf16*)d_ws;
  bf16*  wp        = wq + 768*256;
  float* bias_full = (float*)((char*)d_ws + 524288);

  prep_kernel<<<768, 256, 0, stream>>>(qkv_w, proj_w, bias_table, rel_index,
                                       wq, wp, bias_full);

  (void)hipFuncSetAttribute(reinterpret_cast<const void*>(&win_attn_kernel),
                            hipFuncAttributeMaxDynamicSharedMemorySize, SMEM_BYTES);
  win_attn_kernel<<<4096, 512, SMEM_BYTES, stream>>>(
      x, mask, qkv_b, proj_b, wq, wp, bias_full, out);
}

// Round 3
// 818.545 us; speedup vs baseline: 1.2623x; 1.2623x over previous
//
#include <hip/hip_runtime.h>

// Problem constants
#define NTOK 49          // window tokens (7x7)
#define NW   64          // number of distinct masks
#define SCALEQ 0.17677669529663687f   // 32^-0.5

typedef __bf16 bf16;
typedef __bf16 bf16x4 __attribute__((ext_vector_type(4)));
typedef __bf16 bf16x8 __attribute__((ext_vector_type(8)));
typedef float  f32x4  __attribute__((ext_vector_type(4)));

// ---- LDS layout (units: bf16 elements) ----
// qk  : [4][3920]  per LOCAL head: q [49][40] | k [49][40].
//                  P [49][72] (3528 elems) aliases this after frag-load barrier.
// vts : [4][32][56] v transposed [dd][m], m pad 49..55 zeroed   off 15680 (7168)
// xs  : [49][264]   staged x bf16                               off 22848 (12936)
// ost : [49][264]   attention output (phase 3/4) aliases qk region
// total = 35784 elems = 71568 B -> 2 blocks/CU (143136 <= 163840)
#define QK_OFF  0
#define QK_H    3920
#define K_SUB   1960
#define P_LD    72
#define VTS_OFF 15680
#define XS_OFF  22848
#define SMEM_ELEMS 35784
#define SMEM_BYTES (SMEM_ELEMS*2)
static_assert(SMEM_BYTES == 71568, "lds budget");

// Prep: convert weights to bf16, expand relative-position bias to [8][49][49]
__global__ __launch_bounds__(256) void prep_kernel(
    const float* __restrict__ qkv_w, const float* __restrict__ proj_w,
    const float* __restrict__ bias_table, const int* __restrict__ rel_index,
    bf16* __restrict__ wq, bf16* __restrict__ wp, float* __restrict__ bias_full)
{
  int i = blockIdx.x * 256 + threadIdx.x;
  if (i < 768*256) wq[i] = (bf16)qkv_w[i];
  if (i < 256*256) wp[i] = (bf16)proj_w[i];
  if (i < 8*49*49) {
    int h  = i / 2401;
    int nm = i - h*2401;
    bias_full[i] = bias_table[rel_index[nm]*8 + h];
  }
}

__global__ void __launch_bounds__(512, 4)
win_attn_kernel(const float* __restrict__ x,
                const float* __restrict__ mask,
                const float* __restrict__ qkv_b,
                const float* __restrict__ proj_b,
                const bf16*  __restrict__ wq,
                const bf16*  __restrict__ wp,
                const float* __restrict__ bias_full,
                float* __restrict__ out)
{
  extern __shared__ bf16 smem[];
  const int b    = blockIdx.x;
  const int tid  = threadIdx.x;
  const int wave = tid >> 6;      // 0..7
  const int lane = tid & 63;
  const int quad = lane >> 4;
  const int l16  = lane & 15;
  const int w    = b & (NW - 1);   // mask window index

  bf16* qk  = smem + QK_OFF;
  bf16* vts = smem + VTS_OFF;
  bf16* xs  = smem + XS_OFF;

  f32x4 zero4 = {0.f, 0.f, 0.f, 0.f};

  // ---------- phase 0: stage x -> bf16 LDS; zero vts pads ----------
  {
    const float4* xv = (const float4*)(x + (size_t)b * (NTOK*256));  // 3136 vec4
    for (int i = tid; i < NTOK*64; i += 512) {
      float4 v = xv[i];
      int n = i >> 6, c = (i & 63) * 4;
      bf16x4 pk = {(bf16)v.x, (bf16)v.y, (bf16)v.z, (bf16)v.w};
      *(bf16x4*)(xs + n*264 + c) = pk;
    }
    for (int i = tid; i < 4*32*7; i += 512) {      // vts m in [49,56) := 0
      int hh = i / 224, r = i - hh*224;
      int dd = r / 7, mm = 49 + (r - dd*7);
      vts[(hh*32 + dd)*56 + mm] = (bf16)0.0f;
    }
  }
  __syncthreads();

  const int hl   = wave >> 1;     // local head 0..3
  const int half = wave & 1;

  // Individually named accumulators (round-1/2 lesson: ANY indirection over
  // these — hg-indexed array, by-ref lambda arg — sends them to scratch and
  // costs ~1 GB of HBM spill traffic. Straight-line duplicated code only.)
  f32x4 O0_00, O0_01, O0_10, O0_11;   // head group 0: [row-tile][d-tile]
  f32x4 O1_00, O1_01, O1_10, O1_11;   // head group 1

  // ================= HEAD GROUP 0 (heads 0..3) =================
  {
    // ---------- phase 1: qkv GEMM, cols 0..127 of each segment ----------
    {
      f32x4 acc[3][4];
#pragma unroll
      for (int t = 0; t < 3; ++t)
#pragma unroll
        for (int tr = 0; tr < 4; ++tr) acc[t][tr] = zero4;

      const bf16* wrow[3];
      int jc_[3], s_[3], tl_[3];
#pragma unroll
      for (int t = 0; t < 3; ++t) {
        int tt = wave*3 + t;                 // 0..23
        s_[t]  = tt >> 3;                    // 0=q 1=k 2=v
        tl_[t] = tt & 7;                     // tile within segment
        jc_[t] = s_[t]*256 + 0*128 + tl_[t]*16 + l16;
        wrow[t] = wq + (size_t)jc_[t]*256 + quad*8;
      }
#pragma unroll
      for (int kk = 0; kk < 8; ++kk) {
        bf16x8 afr[4];
#pragma unroll
        for (int tr = 0; tr < 4; ++tr) {
          int m = tr*16 + l16; if (m > 48) m = 48;
          afr[tr] = *(const bf16x8*)(xs + m*264 + quad*8 + kk*32);
        }
#pragma unroll
        for (int t = 0; t < 3; ++t) {
          bf16x8 bfr = *(const bf16x8*)(wrow[t] + kk*32);
#pragma unroll
          for (int tr = 0; tr < 4; ++tr)
            acc[t][tr] = __builtin_amdgcn_mfma_f32_16x16x32_bf16(afr[tr], bfr, acc[t][tr], 0,0,0);
        }
      }
#pragma unroll
      for (int t = 0; t < 3; ++t) {
        float bj = qkv_b[jc_[t]];
        int hh = tl_[t] >> 1;                // local head
        int dd = jc_[t] & 31;
#pragma unroll
        for (int tr = 0; tr < 4; ++tr)
#pragma unroll
          for (int rg = 0; rg < 4; ++rg) {
            int row = tr*16 + quad*4 + rg;
            if (row < 49) {
              float v = acc[t][tr][rg] + bj;
              if (s_[t] == 0)      qk[hh*QK_H + row*40 + dd] = (bf16)(v * SCALEQ);
              else if (s_[t] == 1) qk[hh*QK_H + K_SUB + row*40 + dd] = (bf16)v;
              else                 vts[(hh*32 + dd)*56 + row] = (bf16)v;
            }
          }
      }
    }
    __syncthreads();

    // ---------- phase 2: attention ----------
    {
      const int h = 0*4 + hl;
      const bf16* qh = qk  + hl*QK_H;
      const bf16* kh = qh + K_SUB;
      const bf16* vh = vts + hl*(32*56);
      bf16* Pb = qk + hl*QK_H;

      bf16x8 qf[2], kf[4];
#pragma unroll
      for (int t = 0; t < 2; ++t) {
        int m = (half*2 + t)*16 + l16; if (m > 48) m = 48;
        qf[t] = *(const bf16x8*)(qh + m*40 + quad*8);
      }
#pragma unroll
      for (int t = 0; t < 4; ++t) {
        int m = t*16 + l16; if (m > 48) m = 48;
        kf[t] = *(const bf16x8*)(kh + m*40 + quad*8);
      }
      __syncthreads();        // all q/k frag reads done before P overlays them

      f32x4 S[2][4];
#pragma unroll
      for (int tr = 0; tr < 2; ++tr)
#pragma unroll
        for (int tc = 0; tc < 4; ++tc)
          S[tr][tc] = __builtin_amdgcn_mfma_f32_16x16x32_bf16(qf[tr], kf[tc], zero4, 0,0,0);

      const float* bh = bias_full + h*2401;
      const float* mw = mask + w*2401;
#pragma unroll
      for (int tr2 = 0; tr2 < 2; ++tr2) {
        int tr = half*2 + tr2;
#pragma unroll
        for (int rg = 0; rg < 4; ++rg) {
          int row = tr*16 + quad*4 + rg;
#pragma unroll
          for (int tc = 0; tc < 4; ++tc) {
            int col = tc*16 + l16;
            float v = S[tr2][tc][rg];
            if (col >= 49) v = -1e30f;
            else if (row < 49) {
              int idx = row*49 + col;
              v += bh[idx] + mw[idx];
            }
            S[tr2][tc][rg] = v;
          }
          float mx = fmaxf(fmaxf(S[tr2][0][rg], S[tr2][1][rg]),
                           fmaxf(S[tr2][2][rg], S[tr2][3][rg]));
#pragma unroll
          for (int off = 1; off < 16; off <<= 1)
            mx = fmaxf(mx, __shfl_xor(mx, off));
          float sum = 0.f;
#pragma unroll
          for (int tc = 0; tc < 4; ++tc) {
            float p = __expf(S[tr2][tc][rg] - mx);
            S[tr2][tc][rg] = p;
            sum += p;
          }
#pragma unroll
          for (int off = 1; off < 16; off <<= 1)
            sum += __shfl_xor(sum, off);
          float inv = 1.f / sum;
          if (row < 49) {
#pragma unroll
            for (int tc = 0; tc < 4; ++tc)
              Pb[row*P_LD + tc*16 + l16] = (bf16)(S[tr2][tc][rg] * inv);
          }
        }
      }

      // O = P @ V  (wave reads only P rows it wrote; DS in-order per wave)
      O0_00 = zero4; O0_01 = zero4; O0_10 = zero4; O0_11 = zero4;
#pragma unroll
      for (int kst = 0; kst < 2; ++kst) {
        int mc  = kst*32 + quad*8;
        int mcv = (mc >= 56) ? 0 : mc;
        bf16x8 vf0 = *(const bf16x8*)(vh + l16*56 + mcv);
        bf16x8 vf1 = *(const bf16x8*)(vh + (16 + l16)*56 + mcv);
        int row0 = (half*2 + 0)*16 + l16; if (row0 > 48) row0 = 48;
        bf16x8 pf0 = *(const bf16x8*)(Pb + row0*P_LD + mc);
        O0_00 = __builtin_amdgcn_mfma_f32_16x16x32_bf16(pf0, vf0, O0_00, 0,0,0);
        O0_01 = __builtin_amdgcn_mfma_f32_16x16x32_bf16(pf0, vf1, O0_01, 0,0,0);
        int row1 = (half*2 + 1)*16 + l16; if (row1 > 48) row1 = 48;
        bf16x8 pf1 = *(const bf16x8*)(Pb + row1*P_LD + mc);
        O0_10 = __builtin_amdgcn_mfma_f32_16x16x32_bf16(pf1, vf0, O0_10, 0,0,0);
        O0_11 = __builtin_amdgcn_mfma_f32_16x16x32_bf16(pf1, vf1, O0_11, 0,0,0);
      }
    }
    __syncthreads();    // all P/V reads done before hg=1 rewrites qk/vts
  }

  // ================= HEAD GROUP 1 (heads 4..7) =================
  {
    // ---------- phase 1: qkv GEMM, cols 128..255 of each segment ----------
    {
      f32x4 acc[3][4];
#pragma unroll
      for (int t = 0; t < 3; ++t)
#pragma unroll
        for (int tr = 0; tr < 4; ++tr) acc[t][tr] = zero4;

      const bf16* wrow[3];
      int jc_[3], s_[3], tl_[3];
#pragma unroll
      for (int t = 0; t < 3; ++t) {
        int tt = wave*3 + t;
        s_[t]  = tt >> 3;
        tl_[t] = tt & 7;
        jc_[t] = s_[t]*256 + 1*128 + tl_[t]*16 + l16;
        wrow[t] = wq + (size_t)jc_[t]*256 + quad*8;
      }
#pragma unroll
      for (int kk = 0; kk < 8; ++kk) {
        bf16x8 afr[4];
#pragma unroll
        for (int tr = 0; tr < 4; ++tr) {
          int m = tr*16 + l16; if (m > 48) m = 48;
          afr[tr] = *(const bf16x8*)(xs + m*264 + quad*8 + kk*32);
        }
#pragma unroll
        for (int t = 0; t < 3; ++t) {
          bf16x8 bfr = *(const bf16x8*)(wrow[t] + kk*32);
#pragma unroll
          for (int tr = 0; tr < 4; ++tr)
            acc[t][tr] = __builtin_amdgcn_mfma_f32_16x16x32_bf16(afr[tr], bfr, acc[t][tr], 0,0,0);
        }
      }
#pragma unroll
      for (int t = 0; t < 3; ++t) {
        float bj = qkv_b[jc_[t]];
        int hh = tl_[t] >> 1;
        int dd = jc_[t] & 31;
#pragma unroll
        for (int tr = 0; tr < 4; ++tr)
#pragma unroll
          for (int rg = 0; rg < 4; ++rg) {
            int row = tr*16 + quad*4 + rg;
            if (row < 49) {
              float v = acc[t][tr][rg] + bj;
              if (s_[t] == 0)      qk[hh*QK_H + row*40 + dd] = (bf16)(v * SCALEQ);
              else if (s_[t] == 1) qk[hh*QK_H + K_SUB + row*40 + dd] = (bf16)v;
              else                 vts[(hh*32 + dd)*56 + row] = (bf16)v;
            }
          }
      }
    }
    __syncthreads();

    // ---------- phase 2: attention ----------
    {
      const int h = 1*4 + hl;
      const bf16* qh = qk  + hl*QK_H;
      const bf16* kh = qh + K_SUB;
      const bf16* vh = vts + hl*(32*56);
      bf16* Pb = qk + hl*QK_H;

      bf16x8 qf[2], kf[4];
#pragma unroll
      for (int t = 0; t < 2; ++t) {
        int m = (half*2 + t)*16 + l16; if (m > 48) m = 48;
        qf[t] = *(const bf16x8*)(qh + m*40 + quad*8);
      }
#pragma unroll
      for (int t = 0; t < 4; ++t) {
        int m = t*16 + l16; if (m > 48) m = 48;
        kf[t] = *(const bf16x8*)(kh + m*40 + quad*8);
      }
      __syncthreads();        // all q/k frag reads done before P overlays them

      f32x4 S[2][4];
#pragma unroll
      for (int tr = 0; tr < 2; ++tr)
#pragma unroll
        for (int tc = 0; tc < 4; ++tc)
          S[tr][tc] = __builtin_amdgcn_mfma_f32_16x16x32_bf16(qf[tr], kf[tc], zero4, 0,0,0);

      const float* bh = bias_full + h*2401;
      const float* mw = mask + w*2401;
#pragma unroll
      for (int tr2 = 0; tr2 < 2; ++tr2) {
        int tr = half*2 + tr2;
#pragma unroll
        for (int rg = 0; rg < 4; ++rg) {
          int row = tr*16 + quad*4 + rg;
#pragma unroll
          for (int tc = 0; tc < 4; ++tc) {
            int col = tc*16 + l16;
            float v = S[tr2][tc][rg];
            if (col >= 49) v = -1e30f;
            else if (row < 49) {
              int idx = row*49 + col;
              v += bh[idx] + mw[idx];
            }
            S[tr2][tc][rg] = v;
          }
          float mx = fmaxf(fmaxf(S[tr2][0][rg], S[tr2][1][rg]),
                           fmaxf(S[tr2][2][rg], S[tr2][3][rg]));
#pragma unroll
          for (int off = 1; off < 16; off <<= 1)
            mx = fmaxf(mx, __shfl_xor(mx, off));
          float sum = 0.f;
#pragma unroll
          for (int tc = 0; tc < 4; ++tc) {
            float p = __expf(S[tr2][tc][rg] - mx);
            S[tr2][tc][rg] = p;
            sum += p;
          }
#pragma unroll
          for (int off = 1; off < 16; off <<= 1)
            sum += __shfl_xor(sum, off);
          float inv = 1.f / sum;
          if (row < 49) {
#pragma unroll
            for (int tc = 0; tc < 4; ++tc)
              Pb[row*P_LD + tc*16 + l16] = (bf16)(S[tr2][tc][rg] * inv);
          }
        }
      }

      // O = P @ V
      O1_00 = zero4; O1_01 = zero4; O1_10 = zero4; O1_11 = zero4;
#pragma unroll
      for (int kst = 0; kst < 2; ++kst) {
        int mc  = kst*32 + quad*8;
        int mcv = (mc >= 56) ? 0 : mc;
        bf16x8 vf0 = *(const bf16x8*)(vh + l16*56 + mcv);
        bf16x8 vf1 = *(const bf16x8*)(vh + (16 + l16)*56 + mcv);
        int row0 = (half*2 + 0)*16 + l16; if (row0 > 48) row0 = 48;
        bf16x8 pf0 = *(const bf16x8*)(Pb + row0*P_LD + mc);
        O1_00 = __builtin_amdgcn_mfma_f32_16x16x32_bf16(pf0, vf0, O1_00, 0,0,0);
        O1_01 = __builtin_amdgcn_mfma_f32_16x16x32_bf16(pf0, vf1, O1_01, 0,0,0);
        int row1 = (half*2 + 1)*16 + l16; if (row1 > 48) row1 = 48;
        bf16x8 pf1 = *(const bf16x8*)(Pb + row1*P_LD + mc);
        O1_10 = __builtin_amdgcn_mfma_f32_16x16x32_bf16(pf1, vf0, O1_10, 0,0,0);
        O1_11 = __builtin_amdgcn_mfma_f32_16x16x32_bf16(pf1, vf1, O1_11, 0,0,0);
      }
    }
    __syncthreads();    // all P/V reads done before ost aliases qk
  }

  // ---------- phase 3: O -> ost [49][264] (token-major, channel = h*32+dd) ----------
  bf16* ost = smem;     // aliases qk region (12936 <= 15680)
  {
    int h0 = hl;        // hg=0 global head
    int h1 = 4 + hl;    // hg=1 global head
#pragma unroll
    for (int rg = 0; rg < 4; ++rg) {
      int rowA = (half*2 + 0)*16 + quad*4 + rg;
      if (rowA < 49) {
        ost[rowA*264 + h0*32 + l16]      = (bf16)O0_00[rg];
        ost[rowA*264 + h0*32 + 16 + l16] = (bf16)O0_01[rg];
        ost[rowA*264 + h1*32 + l16]      = (bf16)O1_00[rg];
        ost[rowA*264 + h1*32 + 16 + l16] = (bf16)O1_01[rg];
      }
      int rowB = (half*2 + 1)*16 + quad*4 + rg;
      if (rowB < 49) {
        ost[rowB*264 + h0*32 + l16]      = (bf16)O0_10[rg];
        ost[rowB*264 + h0*32 + 16 + l16] = (bf16)O0_11[rg];
        ost[rowB*264 + h1*32 + l16]      = (bf16)O1_10[rg];
        ost[rowB*264 + h1*32 + 16 + l16] = (bf16)O1_11[rg];
      }
    }
  }
  __syncthreads();

  // ---------- phase 4: out = ost @ Wproj^T + b; wave owns two 16-col tiles ----------
  {
    f32x4 acc[2][4];
#pragma unroll
    for (int t = 0; t < 2; ++t)
#pragma unroll
      for (int tr = 0; tr < 4; ++tr) acc[t][tr] = zero4;
    int oc[2];
    const bf16* wrow[2];
#pragma unroll
    for (int t = 0; t < 2; ++t) {
      oc[t] = (wave*2 + t)*16 + l16;                   // 0..255
      wrow[t] = wp + (size_t)oc[t]*256 + quad*8;
    }
#pragma unroll
    for (int kk = 0; kk < 8; ++kk) {
      bf16x8 afr[4];
#pragma unroll
      for (int tr = 0; tr < 4; ++tr) {
        int m = tr*16 + l16; if (m > 48) m = 48;
        afr[tr] = *(const bf16x8*)(ost + m*264 + quad*8 + kk*32);
      }
#pragma unroll
      for (int t = 0; t < 2; ++t) {
        bf16x8 bfr = *(const bf16x8*)(wrow[t] + kk*32);
#pragma unroll
        for (int tr = 0; tr < 4; ++tr)
          acc[t][tr] = __builtin_amdgcn_mfma_f32_16x16x32_bf16(afr[tr], bfr, acc[t][tr], 0,0,0);
      }
    }
    float* ob = out + (size_t)b * (NTOK*256);
#pragma unroll
    for (int t = 0; t < 2; ++t) {
      float bj = proj_b[oc[t]];
#pragma unroll
      for (int tr = 0; tr < 4; ++tr)
#pragma unroll
        for (int rg = 0; rg < 4; ++rg) {
          int row = tr*16 + quad*4 + rg;
          if (row < 49) ob[row*256 + oc[t]] = acc[t][tr][rg] + bj;
        }
    }
  }
}

extern "C" void kernel_launch(void* const* d_in, const int* in_sizes, int n_in,
                              void* d_out, int out_size, void* d_ws, size_t ws_size,
                              hipStream_t stream) {
  const float* x          = (const float*)d_in[0];
  const float* mask       = (const float*)d_in[1];
  const float* qkv_w      = (const float*)d_in[2];
  const float* qkv_b      = (const float*)d_in[3];
  const float* proj_w     = (const float*)d_in[4];
  const float* proj_b     = (const float*)d_in[5];
  const float* bias_table = (const float*)d_in[6];
  const int*   rel_index  = (const int*)d_in[7];
  float* out = (float*)d_out;

  // workspace: wq bf16 [768*256] | wp bf16 [256*256] | bias_full f32 [8*49*49]
  bf16*  wq        = (bf16*)d_ws;
  bf16*  wp        = wq + 768*256;
  float* bias_full = (float*)((char*)d_ws + 524288);

  prep_kernel<<<768, 256, 0, stream>>>(qkv_w, proj_w, bias_table, rel_index,
                                       wq, wp, bias_full);

  (void)hipFuncSetAttribute(reinterpret_cast<const void*>(&win_attn_kernel),
                            hipFuncAttributeMaxDynamicSharedMemorySize, SMEM_BYTES);
  win_attn_kernel<<<4096, 512, SMEM_BYTES, stream>>>(
      x, mask, qkv_b, proj_b, wq, wp, bias_full, out);
}

// Round 4
// 795.170 us; speedup vs baseline: 1.2994x; 1.0294x over previous
//
#include <hip/hip_runtime.h>

// Problem constants
#define NTOK 49          // window tokens (7x7)
#define NW   64          // number of distinct masks
#define SCALEQ 0.17677669529663687f   // 32^-0.5

typedef __bf16 bf16;
typedef __bf16 bf16x4 __attribute__((ext_vector_type(4)));
typedef __bf16 bf16x8 __attribute__((ext_vector_type(8)));
typedef float  f32x4  __attribute__((ext_vector_type(4)));

// ---- LDS layout (units: bf16 elements) ----
// qk  : [4][3920]  per LOCAL head: q [49][40] | k [49][40].
//                  P [49][72] (3528 elems) aliases this after frag-load barrier.
// vts : [4][32][56] v transposed [dd][m], m pad 49..55 zeroed   off 15680 (7168)
// xs  : [49][264]   staged x bf16                               off 22848 (12936)
// ost : [49][264]   attention output (phase 3/4) aliases qk region
// total = 35784 elems = 71568 B -> 2 blocks/CU (143136 <= 163840)
#define QK_OFF  0
#define QK_H    3920
#define K_SUB   1960
#define P_LD    72
#define VTS_OFF 15680
#define XS_OFF  22848
#define SMEM_ELEMS 35784
#define SMEM_BYTES (SMEM_ELEMS*2)
static_assert(SMEM_BYTES == 71568, "lds budget");

// Prep: convert weights to bf16, expand relative-position bias to [8][49][49]
__global__ __launch_bounds__(256) void prep_kernel(
    const float* __restrict__ qkv_w, const float* __restrict__ proj_w,
    const float* __restrict__ bias_table, const int* __restrict__ rel_index,
    bf16* __restrict__ wq, bf16* __restrict__ wp, float* __restrict__ bias_full)
{
  int i = blockIdx.x * 256 + threadIdx.x;
  if (i < 768*256) wq[i] = (bf16)qkv_w[i];
  if (i < 256*256) wp[i] = (bf16)proj_w[i];
  if (i < 8*49*49) {
    int h  = i / 2401;
    int nm = i - h*2401;
    bias_full[i] = bias_table[rel_index[nm]*8 + h];
  }
}

// waves_per_eu(4,4): PIN the register budget at 128 (512 regs/SIMD / 4 waves).
// Rounds 1-3 lesson: __launch_bounds__(512,4) is only a MINIMUM; the compiler
// chose 8 waves/EU -> 64-VGPR cap -> ~550 MB/dispatch of scratch spill traffic.
// 2 blocks x 8 waves = 16 waves/CU = 4 waves/EU is exactly what LDS allows.
__global__ void __launch_bounds__(512)
__attribute__((amdgpu_waves_per_eu(4, 4)))
win_attn_kernel(const float* __restrict__ x,
                const float* __restrict__ mask,
                const float* __restrict__ qkv_b,
                const float* __restrict__ proj_b,
                const bf16*  __restrict__ wq,
                const bf16*  __restrict__ wp,
                const float* __restrict__ bias_full,
                float* __restrict__ out)
{
  extern __shared__ bf16 smem[];
  const int b    = blockIdx.x;
  const int tid  = threadIdx.x;
  const int wave = tid >> 6;      // 0..7
  const int lane = tid & 63;
  const int quad = lane >> 4;
  const int l16  = lane & 15;
  const int w    = b & (NW - 1);   // mask window index

  bf16* qk  = smem + QK_OFF;
  bf16* vts = smem + VTS_OFF;
  bf16* xs  = smem + XS_OFF;

  f32x4 zero4 = {0.f, 0.f, 0.f, 0.f};

  // ---------- phase 0: stage x -> bf16 LDS; zero vts pads ----------
  {
    const float4* xv = (const float4*)(x + (size_t)b * (NTOK*256));  // 3136 vec4
    for (int i = tid; i < NTOK*64; i += 512) {
      float4 v = xv[i];
      int n = i >> 6, c = (i & 63) * 4;
      bf16x4 pk = {(bf16)v.x, (bf16)v.y, (bf16)v.z, (bf16)v.w};
      *(bf16x4*)(xs + n*264 + c) = pk;
    }
    for (int i = tid; i < 4*32*7; i += 512) {      // vts m in [49,56) := 0
      int hh = i / 224, r = i - hh*224;
      int dd = r / 7, mm = 49 + (r - dd*7);
      vts[(hh*32 + dd)*56 + mm] = (bf16)0.0f;
    }
  }
  __syncthreads();

  const int hl   = wave >> 1;     // local head 0..3
  const int half = wave & 1;

  // O accumulators packed to bf16 right after each PV (outputs pass through
  // bf16 in ost anyway) -> cross-pass live state is 8 regs per head group.
  bf16x4 o0a, o0b, o0c, o0d;   // HG0: (row0,d0) (row0,d1) (row1,d0) (row1,d1)
  bf16x4 o1a, o1b, o1c, o1d;   // HG1

  // ================= HEAD GROUP 0 (heads 0..3) =================
  {
    // ---------- phase 1: qkv GEMM, cols 0..127 of each segment ----------
    {
      f32x4 acc[3][4];
#pragma unroll
      for (int t = 0; t < 3; ++t)
#pragma unroll
        for (int tr = 0; tr < 4; ++tr) acc[t][tr] = zero4;

      const bf16* wrow[3];
      int jc_[3], s_[3], tl_[3];
#pragma unroll
      for (int t = 0; t < 3; ++t) {
        int tt = wave*3 + t;                 // 0..23
        s_[t]  = tt >> 3;                    // 0=q 1=k 2=v
        tl_[t] = tt & 7;                     // tile within segment
        jc_[t] = s_[t]*256 + 0*128 + tl_[t]*16 + l16;
        wrow[t] = wq + (size_t)jc_[t]*256 + quad*8;
      }
#pragma unroll
      for (int kk = 0; kk < 8; ++kk) {
        bf16x8 afr[4];
#pragma unroll
        for (int tr = 0; tr < 4; ++tr) {
          int m = tr*16 + l16; if (m > 48) m = 48;
          afr[tr] = *(const bf16x8*)(xs + m*264 + quad*8 + kk*32);
        }
#pragma unroll
        for (int t = 0; t < 3; ++t) {
          bf16x8 bfr = *(const bf16x8*)(wrow[t] + kk*32);
#pragma unroll
          for (int tr = 0; tr < 4; ++tr)
            acc[t][tr] = __builtin_amdgcn_mfma_f32_16x16x32_bf16(afr[tr], bfr, acc[t][tr], 0,0,0);
        }
      }
#pragma unroll
      for (int t = 0; t < 3; ++t) {
        float bj = qkv_b[jc_[t]];
        int hh = tl_[t] >> 1;                // local head
        int dd = jc_[t] & 31;
#pragma unroll
        for (int tr = 0; tr < 4; ++tr)
#pragma unroll
          for (int rg = 0; rg < 4; ++rg) {
            int row = tr*16 + quad*4 + rg;
            if (row < 49) {
              float v = acc[t][tr][rg] + bj;
              if (s_[t] == 0)      qk[hh*QK_H + row*40 + dd] = (bf16)(v * SCALEQ);
              else if (s_[t] == 1) qk[hh*QK_H + K_SUB + row*40 + dd] = (bf16)v;
              else                 vts[(hh*32 + dd)*56 + row] = (bf16)v;
            }
          }
      }
    }
    __syncthreads();

    // ---------- phase 2: attention ----------
    {
      const int h = 0*4 + hl;
      const bf16* qh = qk  + hl*QK_H;
      const bf16* kh = qh + K_SUB;
      const bf16* vh = vts + hl*(32*56);
      bf16* Pb = qk + hl*QK_H;

      bf16x8 qf[2], kf[4];
#pragma unroll
      for (int t = 0; t < 2; ++t) {
        int m = (half*2 + t)*16 + l16; if (m > 48) m = 48;
        qf[t] = *(const bf16x8*)(qh + m*40 + quad*8);
      }
#pragma unroll
      for (int t = 0; t < 4; ++t) {
        int m = t*16 + l16; if (m > 48) m = 48;
        kf[t] = *(const bf16x8*)(kh + m*40 + quad*8);
      }
      __syncthreads();        // all q/k frag reads done before P overlays them

      f32x4 S[2][4];
#pragma unroll
      for (int tr = 0; tr < 2; ++tr)
#pragma unroll
        for (int tc = 0; tc < 4; ++tc)
          S[tr][tc] = __builtin_amdgcn_mfma_f32_16x16x32_bf16(qf[tr], kf[tc], zero4, 0,0,0);

      const float* bh = bias_full + h*2401;
      const float* mw = mask + w*2401;
#pragma unroll
      for (int tr2 = 0; tr2 < 2; ++tr2) {
        int tr = half*2 + tr2;
#pragma unroll
        for (int rg = 0; rg < 4; ++rg) {
          int row = tr*16 + quad*4 + rg;
#pragma unroll
          for (int tc = 0; tc < 4; ++tc) {
            int col = tc*16 + l16;
            float v = S[tr2][tc][rg];
            if (col >= 49) v = -1e30f;
            else if (row < 49) {
              int idx = row*49 + col;
              v += bh[idx] + mw[idx];
            }
            S[tr2][tc][rg] = v;
          }
          float mx = fmaxf(fmaxf(S[tr2][0][rg], S[tr2][1][rg]),
                           fmaxf(S[tr2][2][rg], S[tr2][3][rg]));
#pragma unroll
          for (int off = 1; off < 16; off <<= 1)
            mx = fmaxf(mx, __shfl_xor(mx, off));
          float sum = 0.f;
#pragma unroll
          for (int tc = 0; tc < 4; ++tc) {
            float p = __expf(S[tr2][tc][rg] - mx);
            S[tr2][tc][rg] = p;
            sum += p;
          }
#pragma unroll
          for (int off = 1; off < 16; off <<= 1)
            sum += __shfl_xor(sum, off);
          float inv = 1.f / sum;
          if (row < 49) {
#pragma unroll
            for (int tc = 0; tc < 4; ++tc)
              Pb[row*P_LD + tc*16 + l16] = (bf16)(S[tr2][tc][rg] * inv);
          }
        }
      }

      // O = P @ V  (wave reads only P rows it wrote; DS in-order per wave)
      f32x4 O00 = zero4, O01 = zero4, O10 = zero4, O11 = zero4;
#pragma unroll
      for (int kst = 0; kst < 2; ++kst) {
        int mc  = kst*32 + quad*8;
        int mcv = (mc >= 56) ? 0 : mc;
        bf16x8 vf0 = *(const bf16x8*)(vh + l16*56 + mcv);
        bf16x8 vf1 = *(const bf16x8*)(vh + (16 + l16)*56 + mcv);
        int row0 = (half*2 + 0)*16 + l16; if (row0 > 48) row0 = 48;
        bf16x8 pf0 = *(const bf16x8*)(Pb + row0*P_LD + mc);
        O00 = __builtin_amdgcn_mfma_f32_16x16x32_bf16(pf0, vf0, O00, 0,0,0);
        O01 = __builtin_amdgcn_mfma_f32_16x16x32_bf16(pf0, vf1, O01, 0,0,0);
        int row1 = (half*2 + 1)*16 + l16; if (row1 > 48) row1 = 48;
        bf16x8 pf1 = *(const bf16x8*)(Pb + row1*P_LD + mc);
        O10 = __builtin_amdgcn_mfma_f32_16x16x32_bf16(pf1, vf0, O10, 0,0,0);
        O11 = __builtin_amdgcn_mfma_f32_16x16x32_bf16(pf1, vf1, O11, 0,0,0);
      }
      // pack to bf16 now: frees 16 f32 regs across the HG1 pass
      o0a = bf16x4{(bf16)O00[0], (bf16)O00[1], (bf16)O00[2], (bf16)O00[3]};
      o0b = bf16x4{(bf16)O01[0], (bf16)O01[1], (bf16)O01[2], (bf16)O01[3]};
      o0c = bf16x4{(bf16)O10[0], (bf16)O10[1], (bf16)O10[2], (bf16)O10[3]};
      o0d = bf16x4{(bf16)O11[0], (bf16)O11[1], (bf16)O11[2], (bf16)O11[3]};
    }
    __syncthreads();    // all P/V reads done before hg=1 rewrites qk/vts
  }

  // ================= HEAD GROUP 1 (heads 4..7) =================
  {
    // ---------- phase 1: qkv GEMM, cols 128..255 of each segment ----------
    {
      f32x4 acc[3][4];
#pragma unroll
      for (int t = 0; t < 3; ++t)
#pragma unroll
        for (int tr = 0; tr < 4; ++tr) acc[t][tr] = zero4;

      const bf16* wrow[3];
      int jc_[3], s_[3], tl_[3];
#pragma unroll
      for (int t = 0; t < 3; ++t) {
        int tt = wave*3 + t;
        s_[t]  = tt >> 3;
        tl_[t] = tt & 7;
        jc_[t] = s_[t]*256 + 1*128 + tl_[t]*16 + l16;
        wrow[t] = wq + (size_t)jc_[t]*256 + quad*8;
      }
#pragma unroll
      for (int kk = 0; kk < 8; ++kk) {
        bf16x8 afr[4];
#pragma unroll
        for (int tr = 0; tr < 4; ++tr) {
          int m = tr*16 + l16; if (m > 48) m = 48;
          afr[tr] = *(const bf16x8*)(xs + m*264 + quad*8 + kk*32);
        }
#pragma unroll
        for (int t = 0; t < 3; ++t) {
          bf16x8 bfr = *(const bf16x8*)(wrow[t] + kk*32);
#pragma unroll
          for (int tr = 0; tr < 4; ++tr)
            acc[t][tr] = __builtin_amdgcn_mfma_f32_16x16x32_bf16(afr[tr], bfr, acc[t][tr], 0,0,0);
        }
      }
#pragma unroll
      for (int t = 0; t < 3; ++t) {
        float bj = qkv_b[jc_[t]];
        int hh = tl_[t] >> 1;
        int dd = jc_[t] & 31;
#pragma unroll
        for (int tr = 0; tr < 4; ++tr)
#pragma unroll
          for (int rg = 0; rg < 4; ++rg) {
            int row = tr*16 + quad*4 + rg;
            if (row < 49) {
              float v = acc[t][tr][rg] + bj;
              if (s_[t] == 0)      qk[hh*QK_H + row*40 + dd] = (bf16)(v * SCALEQ);
              else if (s_[t] == 1) qk[hh*QK_H + K_SUB + row*40 + dd] = (bf16)v;
              else                 vts[(hh*32 + dd)*56 + row] = (bf16)v;
            }
          }
      }
    }
    __syncthreads();

    // ---------- phase 2: attention ----------
    {
      const int h = 1*4 + hl;
      const bf16* qh = qk  + hl*QK_H;
      const bf16* kh = qh + K_SUB;
      const bf16* vh = vts + hl*(32*56);
      bf16* Pb = qk + hl*QK_H;

      bf16x8 qf[2], kf[4];
#pragma unroll
      for (int t = 0; t < 2; ++t) {
        int m = (half*2 + t)*16 + l16; if (m > 48) m = 48;
        qf[t] = *(const bf16x8*)(qh + m*40 + quad*8);
      }
#pragma unroll
      for (int t = 0; t < 4; ++t) {
        int m = t*16 + l16; if (m > 48) m = 48;
        kf[t] = *(const bf16x8*)(kh + m*40 + quad*8);
      }
      __syncthreads();        // all q/k frag reads done before P overlays them

      f32x4 S[2][4];
#pragma unroll
      for (int tr = 0; tr < 2; ++tr)
#pragma unroll
        for (int tc = 0; tc < 4; ++tc)
          S[tr][tc] = __builtin_amdgcn_mfma_f32_16x16x32_bf16(qf[tr], kf[tc], zero4, 0,0,0);

      const float* bh = bias_full + h*2401;
      const float* mw = mask + w*2401;
#pragma unroll
      for (int tr2 = 0; tr2 < 2; ++tr2) {
        int tr = half*2 + tr2;
#pragma unroll
        for (int rg = 0; rg < 4; ++rg) {
          int row = tr*16 + quad*4 + rg;
#pragma unroll
          for (int tc = 0; tc < 4; ++tc) {
            int col = tc*16 + l16;
            float v = S[tr2][tc][rg];
            if (col >= 49) v = -1e30f;
            else if (row < 49) {
              int idx = row*49 + col;
              v += bh[idx] + mw[idx];
            }
            S[tr2][tc][rg] = v;
          }
          float mx = fmaxf(fmaxf(S[tr2][0][rg], S[tr2][1][rg]),
                           fmaxf(S[tr2][2][rg], S[tr2][3][rg]));
#pragma unroll
          for (int off = 1; off < 16; off <<= 1)
            mx = fmaxf(mx, __shfl_xor(mx, off));
          float sum = 0.f;
#pragma unroll
          for (int tc = 0; tc < 4; ++tc) {
            float p = __expf(S[tr2][tc][rg] - mx);
            S[tr2][tc][rg] = p;
            sum += p;
          }
#pragma unroll
          for (int off = 1; off < 16; off <<= 1)
            sum += __shfl_xor(sum, off);
          float inv = 1.f / sum;
          if (row < 49) {
#pragma unroll
            for (int tc = 0; tc < 4; ++tc)
              Pb[row*P_LD + tc*16 + l16] = (bf16)(S[tr2][tc][rg] * inv);
          }
        }
      }

      // O = P @ V
      f32x4 O00 = zero4, O01 = zero4, O10 = zero4, O11 = zero4;
#pragma unroll
      for (int kst = 0; kst < 2; ++kst) {
        int mc  = kst*32 + quad*8;
        int mcv = (mc >= 56) ? 0 : mc;
        bf16x8 vf0 = *(const bf16x8*)(vh + l16*56 + mcv);
        bf16x8 vf1 = *(const bf16x8*)(vh + (16 + l16)*56 + mcv);
        int row0 = (half*2 + 0)*16 + l16; if (row0 > 48) row0 = 48;
        bf16x8 pf0 = *(const bf16x8*)(Pb + row0*P_LD + mc);
        O00 = __builtin_amdgcn_mfma_f32_16x16x32_bf16(pf0, vf0, O00, 0,0,0);
        O01 = __builtin_amdgcn_mfma_f32_16x16x32_bf16(pf0, vf1, O01, 0,0,0);
        int row1 = (half*2 + 1)*16 + l16; if (row1 > 48) row1 = 48;
        bf16x8 pf1 = *(const bf16x8*)(Pb + row1*P_LD + mc);
        O10 = __builtin_amdgcn_mfma_f32_16x16x32_bf16(pf1, vf0, O10, 0,0,0);
        O11 = __builtin_amdgcn_mfma_f32_16x16x32_bf16(pf1, vf1, O11, 0,0,0);
      }
      o1a = bf16x4{(bf16)O00[0], (bf16)O00[1], (bf16)O00[2], (bf16)O00[3]};
      o1b = bf16x4{(bf16)O01[0], (bf16)O01[1], (bf16)O01[2], (bf16)O01[3]};
      o1c = bf16x4{(bf16)O10[0], (bf16)O10[1], (bf16)O10[2], (bf16)O10[3]};
      o1d = bf16x4{(bf16)O11[0], (bf16)O11[1], (bf16)O11[2], (bf16)O11[3]};
    }
    __syncthreads();    // all P/V reads done before ost aliases qk
  }

  // ---------- phase 3: O -> ost [49][264] (token-major, channel = h*32+dd) ----------
  bf16* ost = smem;     // aliases qk region (12936 <= 15680)
  {
    int h0 = hl;        // hg=0 global head
    int h1 = 4 + hl;    // hg=1 global head
#pragma unroll
    for (int rg = 0; rg < 4; ++rg) {
      int rowA = (half*2 + 0)*16 + quad*4 + rg;
      if (rowA < 49) {
        ost[rowA*264 + h0*32 + l16]      = o0a[rg];
        ost[rowA*264 + h0*32 + 16 + l16] = o0b[rg];
        ost[rowA*264 + h1*32 + l16]      = o1a[rg];
        ost[rowA*264 + h1*32 + 16 + l16] = o1b[rg];
      }
      int rowB = (half*2 + 1)*16 + quad*4 + rg;
      if (rowB < 49) {
        ost[rowB*264 + h0*32 + l16]      = o0c[rg];
        ost[rowB*264 + h0*32 + 16 + l16] = o0d[rg];
        ost[rowB*264 + h1*32 + l16]      = o1c[rg];
        ost[rowB*264 + h1*32 + 16 + l16] = o1d[rg];
      }
    }
  }
  __syncthreads();

  // ---------- phase 4: out = ost @ Wproj^T + b; wave owns two 16-col tiles ----------
  {
    f32x4 acc[2][4];
#pragma unroll
    for (int t = 0; t < 2; ++t)
#pragma unroll
      for (int tr = 0; tr < 4; ++tr) acc[t][tr] = zero4;
    int oc[2];
    const bf16* wrow[2];
#pragma unroll
    for (int t = 0; t < 2; ++t) {
      oc[t] = (wave*2 + t)*16 + l16;                   // 0..255
      wrow[t] = wp + (size_t)oc[t]*256 + quad*8;
    }
#pragma unroll
    for (int kk = 0; kk < 8; ++kk) {
      bf16x8 afr[4];
#pragma unroll
      for (int tr = 0; tr < 4; ++tr) {
        int m = tr*16 + l16; if (m > 48) m = 48;
        afr[tr] = *(const bf16x8*)(ost + m*264 + quad*8 + kk*32);
      }
#pragma unroll
      for (int t = 0; t < 2; ++t) {
        bf16x8 bfr = *(const bf16x8*)(wrow[t] + kk*32);
#pragma unroll
        for (int tr = 0; tr < 4; ++tr)
          acc[t][tr] = __builtin_amdgcn_mfma_f32_16x16x32_bf16(afr[tr], bfr, acc[t][tr], 0,0,0);
      }
    }
    float* ob = out + (size_t)b * (NTOK*256);
#pragma unroll
    for (int t = 0; t < 2; ++t) {
      float bj = proj_b[oc[t]];
#pragma unroll
      for (int tr = 0; tr < 4; ++tr)
#pragma unroll
        for (int rg = 0; rg < 4; ++rg) {
          int row = tr*16 + quad*4 + rg;
          if (row < 49) ob[row*256 + oc[t]] = acc[t][tr][rg] + bj;
        }
    }
  }
}

extern "C" void kernel_launch(void* const* d_in, const int* in_sizes, int n_in,
                              void* d_out, int out_size, void* d_ws, size_t ws_size,
                              hipStream_t stream) {
  const float* x          = (const float*)d_in[0];
  const float* mask       = (const float*)d_in[1];
  const float* qkv_w      = (const float*)d_in[2];
  const float* qkv_b      = (const float*)d_in[3];
  const float* proj_w     = (const float*)d_in[4];
  const float* proj_b     = (const float*)d_in[5];
  const float* bias_table = (const float*)d_in[6];
  const int*   rel_index  = (const int*)d_in[7];
  float* out = (float*)d_out;

  // workspace: wq bf16 [768*256] | wp bf16 [256*256] | bias_full f32 [8*49*49]
  bf16*  wq        = (bf16*)d_ws;
  bf16*  wp        = wq + 768*256;
  float* bias_full = (float*)((char*)d_ws + 524288);

  prep_kernel<<<768, 256, 0, stream>>>(qkv_w, proj_w, bias_table, rel_index,
                                       wq, wp, bias_full);

  (void)hipFuncSetAttribute(reinterpret_cast<const void*>(&win_attn_kernel),
                            hipFuncAttributeMaxDynamicSharedMemorySize, SMEM_BYTES);
  win_attn_kernel<<<4096, 512, SMEM_BYTES, stream>>>(
      x, mask, qkv_b, proj_b, wq, wp, bias_full, out);
}